// Round 9
// baseline (214.864 us; speedup 1.0000x reference)
//
#include <hip/hip_runtime.h>
#include <hip/hip_bf16.h>

#define NN 50000
#define NE 800000
#define PAD 64          // slots per node; P(deg>=64) ~ 0 for Poisson(16)
#define CAB 196         // ca/cb sub-blocks inside role-3
#define NBK 391         // coarse buckets of 128 nodes (391*128 = 50048 >= NN)
#define CAPB 2560       // per-bucket edge capacity (mean 2048, +11 sigma)
#define GB_STRIDE 32    // gbase padded 1 counter / 128B line
#define NU 1564         // qkv work units (391*4)
#define NOCT 3128       // attn work units: 391 buckets x 8 octants (16 nodes)

typedef _Float16 fp16x8 __attribute__((ext_vector_type(8)));
typedef _Float16 half2 __attribute__((ext_vector_type(2)));
typedef __attribute__((ext_vector_type(8))) unsigned short ushort8;  // 16 B
typedef __attribute__((ext_vector_type(4))) unsigned short u16x4;    // 8 B
typedef __attribute__((ext_vector_type(4))) float f32x4;

static __device__ __forceinline__ unsigned short f2h(float x) {
    _Float16 h = (_Float16)x;                              // v_cvt_f16_f32 (RNE)
    return __builtin_bit_cast(unsigned short, h);
}
static __device__ __forceinline__ float dot2(half2 a, half2 b, float c) {
#if __has_builtin(__builtin_amdgcn_fdot2)
    return __builtin_amdgcn_fdot2(a, b, c, false);         // v_dot2_f32_f16
#else
    return c + (float)a.x * (float)b.x + (float)a.y * (float)b.y;
#endif
}
static __device__ __forceinline__ half2 h2(unsigned u) {
    return __builtin_bit_cast(half2, u);
}

// ---------------------------------------------------------------------------
// Kernel 1: QKV GEMM + RPE constants + coarse edge bucketing (r6 structure,
// proven). ONLY change: k/v epilogue writes an INTERLEAVED kv row —
// chunk j (16B) = [k dims 4j..4j+3 | v dims 4j..4j+3] — so the attention
// gather needs ONE uint4 load per edge-lane instead of two uint2 loads.
// (r7/r8 cooperative-launch experiments are abandoned: silent no-op under
// the harness in r7, container kill in r8 — coop launch is not capturable.)
// ---------------------------------------------------------------------------
__global__ __launch_bounds__(256) void qkv_gemm(
    const float* __restrict__ feat, const float* __restrict__ w,
    const float* __restrict__ bias, unsigned short* __restrict__ qbuf16,
    unsigned short* __restrict__ kvbuf,
    const float* __restrict__ coord, const float* __restrict__ rpe_w,
    const float* __restrict__ rpe_b, float* __restrict__ ca,
    float* __restrict__ cb,
    const int* __restrict__ graph, unsigned int* __restrict__ gbase,
    unsigned int* __restrict__ ebuf)
{
    const int t  = threadIdx.x;
    const int bx = blockIdx.x;
    int bi, role;
    if (bx < 1536) {
        int rem = bx & 31;
        role = rem >> 3;
        bi   = (bx >> 5) * 8 + (rem & 7);
    } else {
        int idx = bx - 1536;
        role = idx / 7;
        bi   = 384 + idx - role * 7;
    }

    __shared__ __align__(16) unsigned short Ah[128][40];   // 10 KB
    __shared__ __align__(16) unsigned short Bh[128][40];   // 10 KB

    if (role == 3) {                       // aux path (block-uniform branches)
        unsigned int* hist  = (unsigned int*)&Ah[0][0];    // [512] used: 0..390
        unsigned int* sbase = hist + 512;                  // [512] used: 0..390
        for (int u = t; u < NBK; u += 256) hist[u] = 0u;
        __syncthreads();

        int dsts[8], srcs[8];
        bool ok[8];
        const int e0 = bi * 2048;
#pragma unroll
        for (int u = 0; u < 8; ++u) {
            int e = e0 + u * 256 + t;
            ok[u] = (e < NE);
            if (ok[u]) { dsts[u] = graph[e]; srcs[u] = graph[NE + e]; }
        }
#pragma unroll
        for (int u = 0; u < 8; ++u)
            if (ok[u]) atomicAdd(&hist[dsts[u] >> 7], 1u); // LDS atomic
        __syncthreads();
        for (int u = t; u < NBK; u += 256) {
            unsigned int c = hist[u];
            unsigned int s = c ? atomicAdd(&gbase[u * GB_STRIDE], c) : 0u;  // padded global
            sbase[u] = s;
            hist[u]  = 0u;                                 // reuse as local rank
        }
        __syncthreads();
#pragma unroll
        for (int u = 0; u < 8; ++u)
            if (ok[u]) {
                int b = dsts[u] >> 7;
                unsigned int pos = sbase[b] + atomicAdd(&hist[b], 1u);
                if (pos < CAPB)
                    ebuf[(size_t)b * CAPB + pos] =
                        ((unsigned int)(dsts[u] & 127) << 16) | (unsigned int)srcs[u];
            }

        if (bi < CAB) {
            __shared__ float s_rw[12];
            __shared__ float s_rb[4];
            if (t < 12) {
                int h = t / 3, p = t % 3;
                float s = 0.f;
                for (int d = 0; d < 32; ++d) s += rpe_w[(h * 32 + d) * 3 + p];
                s_rw[t] = s;
            } else if (t < 16) {
                int h = t - 12;
                float s = 0.f;
                for (int d = 0; d < 32; ++d) s += rpe_b[h * 32 + d];
                s_rb[h] = s;
            }
            __syncthreads();
            int n = bi * 256 + t;
            if (n < NN) {
                float c0 = coord[n * 3 + 0], c1 = coord[n * 3 + 1], c2 = coord[n * 3 + 2];
#pragma unroll
                for (int h = 0; h < 4; ++h) {
                    float a = c0 * s_rw[h * 3 + 0] + c1 * s_rw[h * 3 + 1] + c2 * s_rw[h * 3 + 2];
                    ca[n * 4 + h] = a;
                    cb[n * 4 + h] = a + s_rb[h];
                }
            }
        }
        return;
    }

    const int bm = bi * 128;
    const int bc = role * 128;             // 0=q 1=k 2=v

    const int wave = t >> 6;
    const int lane = t & 63;
    const int wr = wave & 1;
    const int wc = wave >> 1;
    const int qd = lane >> 4;
    const int l15 = lane & 15;

    f32x4 acc[4][4];
#pragma unroll
    for (int i = 0; i < 4; ++i)
#pragma unroll
        for (int j = 0; j < 4; ++j)
            acc[i][j] = (f32x4){0.f, 0.f, 0.f, 0.f};

    for (int ks = 0; ks < 4; ++ks) {
        const int k0 = ks * 32;
        if (ks) __syncthreads();
        // stage 128x32 slabs: load fp32, cvt to fp16 inline, write b128 to LDS
#pragma unroll
        for (int c = 0; c < 2; ++c) {
            int idx = c * 256 + t;          // 0..511
            int r  = idx >> 2;
            int c8 = (idx & 3) * 8;
            int ga = bm + r;
            ushort8 a8 = (ushort8){0,0,0,0,0,0,0,0};
            if (ga < NN) {
                const float* ap = feat + (size_t)ga * 128 + k0 + c8;
                float4 x = *(const float4*)ap;
                float4 y = *(const float4*)(ap + 4);
                a8 = (ushort8){f2h(x.x), f2h(x.y), f2h(x.z), f2h(x.w),
                               f2h(y.x), f2h(y.y), f2h(y.z), f2h(y.w)};
            }
            *(ushort8*)&Ah[r][c8] = a8;
            const float* bp = w + (size_t)(bc + r) * 128 + k0 + c8;
            float4 bx2 = *(const float4*)bp;
            float4 by2 = *(const float4*)(bp + 4);
            *(ushort8*)&Bh[r][c8] = (ushort8){f2h(bx2.x), f2h(bx2.y), f2h(bx2.z), f2h(bx2.w),
                                              f2h(by2.x), f2h(by2.y), f2h(by2.z), f2h(by2.w)};
        }
        __syncthreads();
        fp16x8 af[4];
#pragma unroll
        for (int i = 0; i < 4; ++i)
            af[i] = *(const fp16x8*)&Ah[wr * 64 + 16 * i + l15][qd * 8];
#pragma unroll
        for (int j = 0; j < 4; ++j) {
            fp16x8 bf = *(const fp16x8*)&Bh[wc * 64 + 16 * j + l15][qd * 8];
#pragma unroll
            for (int i = 0; i < 4; ++i)
                acc[i][j] = __builtin_amdgcn_mfma_f32_16x16x32_f16(af[i], bf, acc[i][j], 0, 0, 0);
        }
    }

    float bj[4];
#pragma unroll
    for (int j = 0; j < 4; ++j)
        bj[j] = bias[bc + wc * 64 + 16 * j + l15];

    // ---- epilogue: per i-group (32 rows x 128 cols) LDS transpose ----
    unsigned short* Ct = &Ah[0][0];        // Ct[32][136] fp16, overlays Ah
    const int isQ = (role == 0);
    const int vsel = (role == 2) ? 4 : 0;  // v occupies shorts 4..7 of each chunk
    const int relRowW = wr * 16 + qd * 4;

    for (int i = 0; i < 4; ++i) {
        __syncthreads();                   // prior phase's LDS reads done
#pragma unroll
        for (int j = 0; j < 4; ++j) {
            int col = wc * 64 + 16 * j + l15;
#pragma unroll
            for (int rg = 0; rg < 4; ++rg)
                Ct[(relRowW + rg) * 136 + col] = f2h(acc[i][j][rg] + bj[j]);
        }
        __syncthreads();
#pragma unroll
        for (int p = 0; p < 2; ++p) {
            int linear = p * 256 + t;
            int rr = linear >> 4;          // 0..31
            int cc = linear & 15;          // 16B chunk (8 cols)
            int absRow = bm + 16 * i + rr + ((rr >> 4) * 48);
            if (absRow < NN) {
                ushort8 val = *(const ushort8*)&Ct[rr * 136 + cc * 8];
                if (isQ) {
                    *(ushort8*)(qbuf16 + (size_t)absRow * 128 + cc * 8) = val;
                } else {
                    // interleaved row: chunk c (8 shorts) = [k 4c..4c+3 | v 4c..4c+3]
                    // this ushort8 = dims cc*8..cc*8+7 -> chunks 2cc and 2cc+1
                    u16x4 lo = (u16x4){val[0], val[1], val[2], val[3]};
                    u16x4 hi = (u16x4){val[4], val[5], val[6], val[7]};
                    unsigned short* rowp = kvbuf + (size_t)absRow * 256;
                    *(u16x4*)(rowp + cc * 16 + vsel)     = lo;
                    *(u16x4*)(rowp + cc * 16 + 8 + vsel) = hi;
                }
            }
        }
    }
}

// ---------------------------------------------------------------------------
// Kernel 2: in-LDS CSR + per-node attention. CHANGES vs r6:
//  - octant units (16 nodes) claimed by global TICKET from a 2048-block grid
//    (8 blocks/CU, all co-resident): near-perfect CU load balance (r6: 6.1
//    blocks/CU -> ~13% tail at 37% occupancy). No inter-block waits, so no
//    deadlock risk, fully graph-capturable.
//  - interleaved kv row: ONE uint4 gather per edge-lane (was k uint2 +
//    v uint2) -> VMEM instruction count and dependency slots halved.
// ---------------------------------------------------------------------------
__global__ __launch_bounds__(256) void attn_fused(
    const unsigned short* __restrict__ qbuf16, const unsigned short* __restrict__ kvbuf,
    const float* __restrict__ ca, const float* __restrict__ cb,
    const unsigned int* __restrict__ gbase, const unsigned int* __restrict__ ebuf,
    unsigned int* __restrict__ ticket, float* __restrict__ out)
{
    __shared__ __align__(16) unsigned short slots[16][64];   // 2 KB
    __shared__ unsigned int ncnt[16];
    __shared__ unsigned int s_u;

    const int t   = threadIdx.x;
    const int j   = t & 31;
    const int h   = j >> 3;
    const int j16 = j * 16;        // byte offset of this lane's 16B kv chunk
    const int j8  = j * 8;         // byte offset of this lane's 8B q chunk
    const int h4  = h * 4;
    const int ln  = t >> 5;        // node-within-group 0..7
    const char* kvp = (const char*)kvbuf;
    const char* cap = (const char*)ca;

    for (;;) {
        if (t == 0) s_u = atomicAdd(ticket, 1u);
        __syncthreads();
        const unsigned u = s_u;
        if (u >= NOCT) return;
        const int b  = (int)(u >> 3);  // bucket 0..390
        const int oc = (int)(u & 7);   // 16-node octant

        if (t < 16) ncnt[t] = 0u;
        __syncthreads();

        int total = (int)gbase[b * GB_STRIDE];
        if (total > CAPB) total = CAPB;
        const unsigned int* eb = ebuf + (size_t)b * CAPB;
        for (int i = t; i < total; i += 256) {
            unsigned int e = eb[i];
            int dl = (int)(e >> 16);                           // 0..127
            if ((dl >> 4) == oc) {
                int ldl = dl & 15;
                unsigned int slot = atomicAdd(&ncnt[ldl], 1u); // LDS atomic
                if (slot < PAD) slots[ldl][slot] = (unsigned short)(e & 0xFFFFu);
            }
        }
        __syncthreads();

        for (int g = 0; g < 2; ++g) {
            const int ldl = g * 8 + ln;
            const int n = b * 128 + oc * 16 + ldl;
            if (n < NN) {
                int d = (int)ncnt[ldl];
                if (d > PAD) d = PAD;
                const unsigned short* sl = &slots[ldl][0];

                const uint2 qv = *(const uint2*)((const char*)qbuf16 + (size_t)n * 256 + j8);
                const half2 qh01 = h2(qv.x);
                const half2 qh23 = h2(qv.y);
                const float cbh = cb[n * 4 + h];

                float4 acc = make_float4(0.f, 0.f, 0.f, 0.f);
                float den = 0.f;

                int i = 0;
                for (; i + 7 < d; i += 8) {
                    ushort8 s8 = *(const ushort8*)(sl + i);    // LDS, 16B
                    unsigned o[8];
#pragma unroll
                    for (int v = 0; v < 8; ++v) o[v] = (unsigned)s8[v] << 9;
                    uint4 kv[8];
                    float aa[8];
#pragma unroll
                    for (int v = 0; v < 8; ++v) kv[v] = *(const uint4*)(kvp + o[v] + j16);
#pragma unroll
                    for (int v = 0; v < 8; ++v) aa[v] = *(const float*)(cap + (o[v] >> 5) + h4);
                    float p[8];
#pragma unroll
                    for (int v = 0; v < 8; ++v)
                        p[v] = dot2(qh01, h2(kv[v].x), dot2(qh23, h2(kv[v].y), 0.f));
#pragma unroll
                    for (int v = 0; v < 8; ++v) p[v] += __shfl_xor(p[v], 1);
#pragma unroll
                    for (int v = 0; v < 8; ++v) p[v] += __shfl_xor(p[v], 2);
#pragma unroll
                    for (int v = 0; v < 8; ++v) p[v] += __shfl_xor(p[v], 4);
                    float e[8];
#pragma unroll
                    for (int v = 0; v < 8; ++v) { e[v] = __expf(p[v] + cbh - aa[v]); den += e[v]; }
#pragma unroll
                    for (int v = 0; v < 8; ++v) {
                        half2 va = h2(kv[v].z);
                        half2 vb = h2(kv[v].w);
                        acc.x += e[v] * (float)va.x;
                        acc.y += e[v] * (float)va.y;
                        acc.z += e[v] * (float)vb.x;
                        acc.w += e[v] * (float)vb.y;
                    }
                }
                for (; i + 3 < d; i += 4) {
                    ushort4 s4 = *(const ushort4*)(sl + i);
                    unsigned o0 = (unsigned)s4.x << 9;
                    unsigned o1 = (unsigned)s4.y << 9;
                    unsigned o2 = (unsigned)s4.z << 9;
                    unsigned o3 = (unsigned)s4.w << 9;
                    uint4 k0 = *(const uint4*)(kvp + o0 + j16);
                    uint4 k1 = *(const uint4*)(kvp + o1 + j16);
                    uint4 k2 = *(const uint4*)(kvp + o2 + j16);
                    uint4 k3 = *(const uint4*)(kvp + o3 + j16);
                    float a0 = *(const float*)(cap + (o0 >> 5) + h4);
                    float a1 = *(const float*)(cap + (o1 >> 5) + h4);
                    float a2 = *(const float*)(cap + (o2 >> 5) + h4);
                    float a3 = *(const float*)(cap + (o3 >> 5) + h4);

                    float p0 = dot2(qh01, h2(k0.x), dot2(qh23, h2(k0.y), 0.f));
                    float p1 = dot2(qh01, h2(k1.x), dot2(qh23, h2(k1.y), 0.f));
                    float p2 = dot2(qh01, h2(k2.x), dot2(qh23, h2(k2.y), 0.f));
                    float p3 = dot2(qh01, h2(k3.x), dot2(qh23, h2(k3.y), 0.f));
                    p0 += __shfl_xor(p0, 1); p1 += __shfl_xor(p1, 1);
                    p2 += __shfl_xor(p2, 1); p3 += __shfl_xor(p3, 1);
                    p0 += __shfl_xor(p0, 2); p1 += __shfl_xor(p1, 2);
                    p2 += __shfl_xor(p2, 2); p3 += __shfl_xor(p3, 2);
                    p0 += __shfl_xor(p0, 4); p1 += __shfl_xor(p1, 4);
                    p2 += __shfl_xor(p2, 4); p3 += __shfl_xor(p3, 4);

                    float e0 = __expf(p0 + cbh - a0);
                    float e1 = __expf(p1 + cbh - a1);
                    float e2 = __expf(p2 + cbh - a2);
                    float e3 = __expf(p3 + cbh - a3);
                    den += (e0 + e1) + (e2 + e3);
                    half2 v0a = h2(k0.z), v0b = h2(k0.w);
                    half2 v1a = h2(k1.z), v1b = h2(k1.w);
                    half2 v2a = h2(k2.z), v2b = h2(k2.w);
                    half2 v3a = h2(k3.z), v3b = h2(k3.w);
                    acc.x += e0 * (float)v0a.x + e1 * (float)v1a.x + e2 * (float)v2a.x + e3 * (float)v3a.x;
                    acc.y += e0 * (float)v0a.y + e1 * (float)v1a.y + e2 * (float)v2a.y + e3 * (float)v3a.y;
                    acc.z += e0 * (float)v0b.x + e1 * (float)v1b.x + e2 * (float)v2b.x + e3 * (float)v3b.x;
                    acc.w += e0 * (float)v0b.y + e1 * (float)v1b.y + e2 * (float)v2b.y + e3 * (float)v3b.y;
                }
                for (; i < d; ++i) {
                    unsigned o0 = (unsigned)sl[i] << 9;
                    uint4 k0 = *(const uint4*)(kvp + o0 + j16);
                    float a0 = *(const float*)(cap + (o0 >> 5) + h4);
                    float p0 = dot2(qh01, h2(k0.x), dot2(qh23, h2(k0.y), 0.f));
                    p0 += __shfl_xor(p0, 1);
                    p0 += __shfl_xor(p0, 2);
                    p0 += __shfl_xor(p0, 4);
                    float e = __expf(p0 + cbh - a0);
                    den += e;
                    half2 va = h2(k0.z);
                    half2 vb = h2(k0.w);
                    acc.x += e * (float)va.x;
                    acc.y += e * (float)va.y;
                    acc.z += e * (float)vb.x;
                    acc.w += e * (float)vb.y;
                }

                float inv = (den > 0.f) ? 1.0f / den : 0.f;
                float4 o = make_float4(acc.x * inv, acc.y * inv, acc.z * inv, acc.w * inv);
                ((float4*)(out + (size_t)n * 128))[j] = o;
            }
        }
        __syncthreads();               // LDS/s_u reuse guard before next ticket
    }
}

extern "C" void kernel_launch(void* const* d_in, const int* in_sizes, int n_in,
                              void* d_out, int out_size, void* d_ws, size_t ws_size,
                              hipStream_t stream) {
    const float* feat  = (const float*)d_in[0];
    const float* coord = (const float*)d_in[1];
    const int*   graph = (const int*)d_in[2];
    const float* qkv_w = (const float*)d_in[3];
    const float* qkv_b = (const float*)d_in[4];
    const float* rpe_w = (const float*)d_in[5];
    const float* rpe_b = (const float*)d_in[6];
    float* out = (float*)d_out;

    unsigned short* qbuf16 = (unsigned short*)d_ws;                       // NN x 128 f16   (12.8 MB)
    unsigned short* kvbuf  = qbuf16 + (size_t)NN * 128;                   // NN x 256 f16   (25.6 MB)
    float* ca = (float*)(kvbuf + (size_t)NN * 256);                       // NN x 4         (0.8 MB)
    float* cb = ca + (size_t)NN * 4;                                      // NN x 4         (0.8 MB)
    unsigned int* gbase  = (unsigned int*)(cb + (size_t)NN * 4);          // NBK x 32       (50 KB)
    unsigned int* ticket = gbase + (size_t)NBK * GB_STRIDE;               // 32 (1 used)
    unsigned int* ebuf   = ticket + GB_STRIDE;                            // NBK x CAPB     (4.0 MB)

    // zero gbase counters + ticket in one memset
    hipMemsetAsync(gbase, 0, (size_t)(NBK + 1) * GB_STRIDE * sizeof(unsigned int), stream);

    qkv_gemm  <<<dim3(NU), 256, 0, stream>>>(feat, qkv_w, qkv_b, qbuf16, kvbuf,
                                             coord, rpe_w, rpe_b, ca, cb,
                                             graph, gbase, ebuf);
    attn_fused<<<dim3(2048), 256, 0, stream>>>(qbuf16, kvbuf, ca, cb,
                                               gbase, ebuf, ticket, out);
}

// Round 10
// 200.186 us; speedup vs baseline: 1.0733x; 1.0733x over previous
//
#include <hip/hip_runtime.h>
#include <hip/hip_bf16.h>

#define NN 50000
#define NE 800000
#define PAD 64          // slots per node; P(deg>=64) ~ 0 for Poisson(16)
#define CAB 196         // ca/cb sub-blocks inside role-3
#define NBK 391         // coarse buckets of 128 nodes (391*128 = 50048 >= NN)
#define CAPB 2560       // per-bucket edge capacity (mean 2048, +11 sigma)
#define GB_STRIDE 32    // gbase padded 1 counter / 128B line
#define NU 1564         // qkv work units (391*4)
#define NHALF 782       // attn work units: 391 buckets x 2 halves (64 nodes)

typedef _Float16 fp16x8 __attribute__((ext_vector_type(8)));
typedef _Float16 half2 __attribute__((ext_vector_type(2)));
typedef __attribute__((ext_vector_type(8))) unsigned short ushort8;  // 16 B
typedef __attribute__((ext_vector_type(4))) float f32x4;

static __device__ __forceinline__ unsigned short f2h(float x) {
    _Float16 h = (_Float16)x;                              // v_cvt_f16_f32 (RNE)
    return __builtin_bit_cast(unsigned short, h);
}
static __device__ __forceinline__ float dot2(half2 a, half2 b, float c) {
#if __has_builtin(__builtin_amdgcn_fdot2)
    return __builtin_amdgcn_fdot2(a, b, c, false);         // v_dot2_f32_f16
#else
    return c + (float)a.x * (float)b.x + (float)a.y * (float)b.y;
#endif
}
static __device__ __forceinline__ half2 h2(unsigned u) {
    return __builtin_bit_cast(half2, u);
}

// ---------------------------------------------------------------------------
// Kernel 1: QKV GEMM + RPE constants + coarse edge bucketing.
// EXACT r6 kernel (proven; with the XCD-swizzle mapping that cut qkv to
// ~38us and the k-half/v-half kvbuf layout). r9's kv-interleave reverted:
// modeled contribution was ~0 and it confounds attribution.
// ---------------------------------------------------------------------------
__global__ __launch_bounds__(256) void qkv_gemm(
    const float* __restrict__ feat, const float* __restrict__ w,
    const float* __restrict__ bias, unsigned short* __restrict__ qbuf16,
    unsigned short* __restrict__ kvbuf,
    const float* __restrict__ coord, const float* __restrict__ rpe_w,
    const float* __restrict__ rpe_b, float* __restrict__ ca,
    float* __restrict__ cb,
    const int* __restrict__ graph, unsigned int* __restrict__ gbase,
    unsigned int* __restrict__ ebuf)
{
    const int t  = threadIdx.x;
    const int bx = blockIdx.x;
    int bi, role;
    if (bx < 1536) {
        int rem = bx & 31;
        role = rem >> 3;
        bi   = (bx >> 5) * 8 + (rem & 7);
    } else {
        int idx = bx - 1536;
        role = idx / 7;
        bi   = 384 + idx - role * 7;
    }

    __shared__ __align__(16) unsigned short Ah[128][40];   // 10 KB
    __shared__ __align__(16) unsigned short Bh[128][40];   // 10 KB

    if (role == 3) {                       // aux path (block-uniform branches)
        unsigned int* hist  = (unsigned int*)&Ah[0][0];    // [512] used: 0..390
        unsigned int* sbase = hist + 512;                  // [512] used: 0..390
        for (int u = t; u < NBK; u += 256) hist[u] = 0u;
        __syncthreads();

        int dsts[8], srcs[8];
        bool ok[8];
        const int e0 = bi * 2048;
#pragma unroll
        for (int u = 0; u < 8; ++u) {
            int e = e0 + u * 256 + t;
            ok[u] = (e < NE);
            if (ok[u]) { dsts[u] = graph[e]; srcs[u] = graph[NE + e]; }
        }
#pragma unroll
        for (int u = 0; u < 8; ++u)
            if (ok[u]) atomicAdd(&hist[dsts[u] >> 7], 1u); // LDS atomic
        __syncthreads();
        for (int u = t; u < NBK; u += 256) {
            unsigned int c = hist[u];
            unsigned int s = c ? atomicAdd(&gbase[u * GB_STRIDE], c) : 0u;  // padded global
            sbase[u] = s;
            hist[u]  = 0u;                                 // reuse as local rank
        }
        __syncthreads();
#pragma unroll
        for (int u = 0; u < 8; ++u)
            if (ok[u]) {
                int b = dsts[u] >> 7;
                unsigned int pos = sbase[b] + atomicAdd(&hist[b], 1u);
                if (pos < CAPB)
                    ebuf[(size_t)b * CAPB + pos] =
                        ((unsigned int)(dsts[u] & 127) << 16) | (unsigned int)srcs[u];
            }

        if (bi < CAB) {
            __shared__ float s_rw[12];
            __shared__ float s_rb[4];
            if (t < 12) {
                int h = t / 3, p = t % 3;
                float s = 0.f;
                for (int d = 0; d < 32; ++d) s += rpe_w[(h * 32 + d) * 3 + p];
                s_rw[t] = s;
            } else if (t < 16) {
                int h = t - 12;
                float s = 0.f;
                for (int d = 0; d < 32; ++d) s += rpe_b[h * 32 + d];
                s_rb[h] = s;
            }
            __syncthreads();
            int n = bi * 256 + t;
            if (n < NN) {
                float c0 = coord[n * 3 + 0], c1 = coord[n * 3 + 1], c2 = coord[n * 3 + 2];
#pragma unroll
                for (int h = 0; h < 4; ++h) {
                    float a = c0 * s_rw[h * 3 + 0] + c1 * s_rw[h * 3 + 1] + c2 * s_rw[h * 3 + 2];
                    ca[n * 4 + h] = a;
                    cb[n * 4 + h] = a + s_rb[h];
                }
            }
        }
        return;
    }

    const int bm = bi * 128;
    const int bc = role * 128;             // 0=q 1=k 2=v

    const int wave = t >> 6;
    const int lane = t & 63;
    const int wr = wave & 1;
    const int wc = wave >> 1;
    const int qd = lane >> 4;
    const int l15 = lane & 15;

    f32x4 acc[4][4];
#pragma unroll
    for (int i = 0; i < 4; ++i)
#pragma unroll
        for (int j = 0; j < 4; ++j)
            acc[i][j] = (f32x4){0.f, 0.f, 0.f, 0.f};

    for (int ks = 0; ks < 4; ++ks) {
        const int k0 = ks * 32;
        if (ks) __syncthreads();
        // stage 128x32 slabs: load fp32, cvt to fp16 inline, write b128 to LDS
#pragma unroll
        for (int c = 0; c < 2; ++c) {
            int idx = c * 256 + t;          // 0..511
            int r  = idx >> 2;
            int c8 = (idx & 3) * 8;
            int ga = bm + r;
            ushort8 a8 = (ushort8){0,0,0,0,0,0,0,0};
            if (ga < NN) {
                const float* ap = feat + (size_t)ga * 128 + k0 + c8;
                float4 x = *(const float4*)ap;
                float4 y = *(const float4*)(ap + 4);
                a8 = (ushort8){f2h(x.x), f2h(x.y), f2h(x.z), f2h(x.w),
                               f2h(y.x), f2h(y.y), f2h(y.z), f2h(y.w)};
            }
            *(ushort8*)&Ah[r][c8] = a8;
            const float* bp = w + (size_t)(bc + r) * 128 + k0 + c8;
            float4 bx2 = *(const float4*)bp;
            float4 by2 = *(const float4*)(bp + 4);
            *(ushort8*)&Bh[r][c8] = (ushort8){f2h(bx2.x), f2h(bx2.y), f2h(bx2.z), f2h(bx2.w),
                                              f2h(by2.x), f2h(by2.y), f2h(by2.z), f2h(by2.w)};
        }
        __syncthreads();
        fp16x8 af[4];
#pragma unroll
        for (int i = 0; i < 4; ++i)
            af[i] = *(const fp16x8*)&Ah[wr * 64 + 16 * i + l15][qd * 8];
#pragma unroll
        for (int j = 0; j < 4; ++j) {
            fp16x8 bf = *(const fp16x8*)&Bh[wc * 64 + 16 * j + l15][qd * 8];
#pragma unroll
            for (int i = 0; i < 4; ++i)
                acc[i][j] = __builtin_amdgcn_mfma_f32_16x16x32_f16(af[i], bf, acc[i][j], 0, 0, 0);
        }
    }

    float bj[4];
#pragma unroll
    for (int j = 0; j < 4; ++j)
        bj[j] = bias[bc + wc * 64 + 16 * j + l15];

    // ---- epilogue: per i-group (32 rows x 128 cols) LDS transpose ----
    unsigned short* Ct = &Ah[0][0];        // Ct[32][136] fp16, overlays Ah
    const int isQ = (role == 0);
    const int half = (role == 1) ? 0 : 128;
    const int relRowW = wr * 16 + qd * 4;

    for (int i = 0; i < 4; ++i) {
        __syncthreads();                   // prior phase's LDS reads done
#pragma unroll
        for (int j = 0; j < 4; ++j) {
            int col = wc * 64 + 16 * j + l15;
#pragma unroll
            for (int rg = 0; rg < 4; ++rg)
                Ct[(relRowW + rg) * 136 + col] = f2h(acc[i][j][rg] + bj[j]);
        }
        __syncthreads();
#pragma unroll
        for (int p = 0; p < 2; ++p) {
            int linear = p * 256 + t;
            int rr = linear >> 4;          // 0..31
            int cc = linear & 15;          // 16B chunk (8 cols)
            int absRow = bm + 16 * i + rr + ((rr >> 4) * 48);
            if (absRow < NN) {
                ushort8 val = *(const ushort8*)&Ct[rr * 136 + cc * 8];
                if (isQ) *(ushort8*)(qbuf16 + (size_t)absRow * 128 + cc * 8) = val;
                else     *(ushort8*)(kvbuf + (size_t)absRow * 256 + half + cc * 8) = val;
            }
        }
    }
}

// ---------------------------------------------------------------------------
// Kernel 2: in-LDS CSR + per-node attention. SINGLE change vs r6:
// HALF-BUCKET units (64 nodes) -> the ebuf scan replication drops 4x -> 2x
// (total edge-reads 3.2M -> 1.6M; modeled scan cost ~30us -> ~15us), with
// the r9-proven ticket queue over a 2048-block persistent grid for dynamic
// CU balance (782 static blocks would give a 3-vs-4 units/CU ~30% tail).
// Gather body + k/v separate uint2 loads = exact r6 (proven).
// ---------------------------------------------------------------------------
__global__ __launch_bounds__(256) void attn_fused(
    const unsigned short* __restrict__ qbuf16, const unsigned short* __restrict__ kvbuf,
    const float* __restrict__ ca, const float* __restrict__ cb,
    const unsigned int* __restrict__ gbase, const unsigned int* __restrict__ ebuf,
    unsigned int* __restrict__ ticket, float* __restrict__ out)
{
    __shared__ __align__(16) unsigned short slots[64][64];   // 8 KB
    __shared__ unsigned int ncnt[64];
    __shared__ unsigned int s_u;

    const int t  = threadIdx.x;
    const int j  = t & 31;
    const int h  = j >> 3;
    const int j8 = j * 8;
    const int h4 = h * 4;
    const int ln = t >> 5;                 // node-stream 0..7
    const char* kvp = (const char*)kvbuf;
    const char* cap = (const char*)ca;

    for (;;) {
        if (t == 0) s_u = atomicAdd(ticket, 1u);
        __syncthreads();
        const unsigned u = s_u;
        if (u >= NHALF) return;
        const int b  = (int)(u >> 1);      // bucket 0..390
        const int hf = (int)(u & 1);       // 64-node half

        if (t < 64) ncnt[t] = 0u;
        __syncthreads();

        int total = (int)gbase[b * GB_STRIDE];
        if (total > CAPB) total = CAPB;
        const unsigned int* eb = ebuf + (size_t)b * CAPB;
        for (int i = t; i < total; i += 256) {
            unsigned int e = eb[i];
            int dl = (int)(e >> 16);                           // 0..127
            if ((dl >> 6) == hf) {
                int ldl = dl & 63;
                unsigned int slot = atomicAdd(&ncnt[ldl], 1u); // LDS atomic
                if (slot < PAD) slots[ldl][slot] = (unsigned short)(e & 0xFFFFu);
            }
        }
        __syncthreads();

        for (int g = 0; g < 8; ++g) {
            const int ldl = g * 8 + ln;
            const int n = b * 128 + hf * 64 + ldl;
            if (n < NN) {
                int d = (int)ncnt[ldl];
                if (d > PAD) d = PAD;
                const unsigned short* sl = &slots[ldl][0];

                const uint2 qv = *(const uint2*)((const char*)qbuf16 + (size_t)n * 256 + j8);
                const half2 qh01 = h2(qv.x);
                const half2 qh23 = h2(qv.y);
                const float cbh = cb[n * 4 + h];

                float4 acc = make_float4(0.f, 0.f, 0.f, 0.f);
                float den = 0.f;

                int i = 0;
                for (; i + 7 < d; i += 8) {
                    ushort8 s8 = *(const ushort8*)(sl + i);    // LDS, 16B
                    unsigned o[8];
#pragma unroll
                    for (int v = 0; v < 8; ++v) o[v] = (unsigned)s8[v] << 9;
                    uint2 kk[8], vv[8];
                    float aa[8];
#pragma unroll
                    for (int v = 0; v < 8; ++v) kk[v] = *(const uint2*)(kvp + o[v] + j8);
#pragma unroll
                    for (int v = 0; v < 8; ++v) vv[v] = *(const uint2*)(kvp + o[v] + 256 + j8);
#pragma unroll
                    for (int v = 0; v < 8; ++v) aa[v] = *(const float*)(cap + (o[v] >> 5) + h4);
                    float p[8];
#pragma unroll
                    for (int v = 0; v < 8; ++v)
                        p[v] = dot2(qh01, h2(kk[v].x), dot2(qh23, h2(kk[v].y), 0.f));
#pragma unroll
                    for (int v = 0; v < 8; ++v) p[v] += __shfl_xor(p[v], 1);
#pragma unroll
                    for (int v = 0; v < 8; ++v) p[v] += __shfl_xor(p[v], 2);
#pragma unroll
                    for (int v = 0; v < 8; ++v) p[v] += __shfl_xor(p[v], 4);
                    float e[8];
#pragma unroll
                    for (int v = 0; v < 8; ++v) { e[v] = __expf(p[v] + cbh - aa[v]); den += e[v]; }
#pragma unroll
                    for (int v = 0; v < 8; ++v) {
                        half2 va = h2(vv[v].x);
                        half2 vb = h2(vv[v].y);
                        acc.x += e[v] * (float)va.x;
                        acc.y += e[v] * (float)va.y;
                        acc.z += e[v] * (float)vb.x;
                        acc.w += e[v] * (float)vb.y;
                    }
                }
                for (; i + 3 < d; i += 4) {
                    ushort4 s4 = *(const ushort4*)(sl + i);
                    unsigned o0 = (unsigned)s4.x << 9;
                    unsigned o1 = (unsigned)s4.y << 9;
                    unsigned o2 = (unsigned)s4.z << 9;
                    unsigned o3 = (unsigned)s4.w << 9;
                    uint2 k0 = *(const uint2*)(kvp + o0 + j8);
                    uint2 k1 = *(const uint2*)(kvp + o1 + j8);
                    uint2 k2 = *(const uint2*)(kvp + o2 + j8);
                    uint2 k3 = *(const uint2*)(kvp + o3 + j8);
                    uint2 v0 = *(const uint2*)(kvp + o0 + 256 + j8);
                    uint2 v1 = *(const uint2*)(kvp + o1 + 256 + j8);
                    uint2 v2 = *(const uint2*)(kvp + o2 + 256 + j8);
                    uint2 v3 = *(const uint2*)(kvp + o3 + 256 + j8);
                    float a0 = *(const float*)(cap + (o0 >> 5) + h4);
                    float a1 = *(const float*)(cap + (o1 >> 5) + h4);
                    float a2 = *(const float*)(cap + (o2 >> 5) + h4);
                    float a3 = *(const float*)(cap + (o3 >> 5) + h4);

                    float p0 = dot2(qh01, h2(k0.x), dot2(qh23, h2(k0.y), 0.f));
                    float p1 = dot2(qh01, h2(k1.x), dot2(qh23, h2(k1.y), 0.f));
                    float p2 = dot2(qh01, h2(k2.x), dot2(qh23, h2(k2.y), 0.f));
                    float p3 = dot2(qh01, h2(k3.x), dot2(qh23, h2(k3.y), 0.f));
                    p0 += __shfl_xor(p0, 1); p1 += __shfl_xor(p1, 1);
                    p2 += __shfl_xor(p2, 1); p3 += __shfl_xor(p3, 1);
                    p0 += __shfl_xor(p0, 2); p1 += __shfl_xor(p1, 2);
                    p2 += __shfl_xor(p2, 2); p3 += __shfl_xor(p3, 2);
                    p0 += __shfl_xor(p0, 4); p1 += __shfl_xor(p1, 4);
                    p2 += __shfl_xor(p2, 4); p3 += __shfl_xor(p3, 4);

                    float e0 = __expf(p0 + cbh - a0);
                    float e1 = __expf(p1 + cbh - a1);
                    float e2 = __expf(p2 + cbh - a2);
                    float e3 = __expf(p3 + cbh - a3);
                    den += (e0 + e1) + (e2 + e3);
                    half2 v0a = h2(v0.x), v0b = h2(v0.y);
                    half2 v1a = h2(v1.x), v1b = h2(v1.y);
                    half2 v2a = h2(v2.x), v2b = h2(v2.y);
                    half2 v3a = h2(v3.x), v3b = h2(v3.y);
                    acc.x += e0 * (float)v0a.x + e1 * (float)v1a.x + e2 * (float)v2a.x + e3 * (float)v3a.x;
                    acc.y += e0 * (float)v0a.y + e1 * (float)v1a.y + e2 * (float)v2a.y + e3 * (float)v3a.y;
                    acc.z += e0 * (float)v0b.x + e1 * (float)v1b.x + e2 * (float)v2b.x + e3 * (float)v3b.x;
                    acc.w += e0 * (float)v0b.y + e1 * (float)v1b.y + e2 * (float)v2b.y + e3 * (float)v3b.y;
                }
                for (; i < d; ++i) {
                    unsigned o0 = (unsigned)sl[i] << 9;
                    uint2 k0 = *(const uint2*)(kvp + o0 + j8);
                    uint2 v0 = *(const uint2*)(kvp + o0 + 256 + j8);
                    float a0 = *(const float*)(cap + (o0 >> 5) + h4);
                    float p0 = dot2(qh01, h2(k0.x), dot2(qh23, h2(k0.y), 0.f));
                    p0 += __shfl_xor(p0, 1);
                    p0 += __shfl_xor(p0, 2);
                    p0 += __shfl_xor(p0, 4);
                    float e = __expf(p0 + cbh - a0);
                    den += e;
                    half2 va = h2(v0.x);
                    half2 vb = h2(v0.y);
                    acc.x += e * (float)va.x;
                    acc.y += e * (float)va.y;
                    acc.z += e * (float)vb.x;
                    acc.w += e * (float)vb.y;
                }

                float inv = (den > 0.f) ? 1.0f / den : 0.f;
                float4 o = make_float4(acc.x * inv, acc.y * inv, acc.z * inv, acc.w * inv);
                ((float4*)(out + (size_t)n * 128))[j] = o;
            }
        }
        __syncthreads();               // LDS/s_u reuse guard before next ticket
    }
}

extern "C" void kernel_launch(void* const* d_in, const int* in_sizes, int n_in,
                              void* d_out, int out_size, void* d_ws, size_t ws_size,
                              hipStream_t stream) {
    const float* feat  = (const float*)d_in[0];
    const float* coord = (const float*)d_in[1];
    const int*   graph = (const int*)d_in[2];
    const float* qkv_w = (const float*)d_in[3];
    const float* qkv_b = (const float*)d_in[4];
    const float* rpe_w = (const float*)d_in[5];
    const float* rpe_b = (const float*)d_in[6];
    float* out = (float*)d_out;

    unsigned short* qbuf16 = (unsigned short*)d_ws;                       // NN x 128 f16   (12.8 MB)
    unsigned short* kvbuf  = qbuf16 + (size_t)NN * 128;                   // NN x 256 f16   (25.6 MB)
    float* ca = (float*)(kvbuf + (size_t)NN * 256);                       // NN x 4         (0.8 MB)
    float* cb = ca + (size_t)NN * 4;                                      // NN x 4         (0.8 MB)
    unsigned int* gbase  = (unsigned int*)(cb + (size_t)NN * 4);          // NBK x 32       (50 KB)
    unsigned int* ticket = gbase + (size_t)NBK * GB_STRIDE;               // 32 (1 used)
    unsigned int* ebuf   = ticket + GB_STRIDE;                            // NBK x CAPB     (4.0 MB)

    // zero gbase counters + ticket in one memset
    hipMemsetAsync(gbase, 0, (size_t)(NBK + 1) * GB_STRIDE * sizeof(unsigned int), stream);

    qkv_gemm  <<<dim3(NU), 256, 0, stream>>>(feat, qkv_w, qkv_b, qbuf16, kvbuf,
                                             coord, rpe_w, rpe_b, ca, cb,
                                             graph, gbase, ebuf);
    attn_fused<<<dim3(2048), 256, 0, stream>>>(qbuf16, kvbuf, ca, cb,
                                               gbase, ebuf, ticket, out);
}

// Round 12
// 180.029 us; speedup vs baseline: 1.1935x; 1.1120x over previous
//
#include <hip/hip_runtime.h>
#include <hip/hip_bf16.h>

#define NN 50000
#define NE 800000
#define PAD 64          // slots per node; P(deg>=64) ~ 0 for Poisson(16)
#define CAB 196         // ca/cb sub-blocks inside role-3
#define NBK 391         // coarse buckets of 128 nodes (391*128 = 50048 >= NN)
#define CAPB 2560       // per-bucket edge capacity (mean 2048, +11 sigma)
#define GB_STRIDE 32    // gbase padded 1 counter / 128B line
#define NU 1564         // qkv work units (391*4)

typedef _Float16 fp16x8 __attribute__((ext_vector_type(8)));
typedef _Float16 half2 __attribute__((ext_vector_type(2)));
typedef __attribute__((ext_vector_type(8))) unsigned short ushort8;  // 16 B
typedef __attribute__((ext_vector_type(4))) float f32x4;

static __device__ __forceinline__ unsigned short f2h(float x) {
    _Float16 h = (_Float16)x;                              // v_cvt_f16_f32 (RNE)
    return __builtin_bit_cast(unsigned short, h);
}
static __device__ __forceinline__ float dot2(half2 a, half2 b, float c) {
#if __has_builtin(__builtin_amdgcn_fdot2)
    return __builtin_amdgcn_fdot2(a, b, c, false);         // v_dot2_f32_f16
#else
    return c + (float)a.x * (float)b.x + (float)a.y * (float)b.y;
#endif
}
static __device__ __forceinline__ half2 h2(unsigned u) {
    return __builtin_bit_cast(half2, u);
}

// ---------------------------------------------------------------------------
// Kernel 1: QKV GEMM + RPE constants + coarse edge bucketing.
// EXACT r6 kernel (proven best total: 182.1us) with the XCD-swizzle block
// mapping. Untouched.
// ---------------------------------------------------------------------------
__global__ __launch_bounds__(256) void qkv_gemm(
    const float* __restrict__ feat, const float* __restrict__ w,
    const float* __restrict__ bias, unsigned short* __restrict__ qbuf16,
    unsigned short* __restrict__ kvbuf,
    const float* __restrict__ coord, const float* __restrict__ rpe_w,
    const float* __restrict__ rpe_b, float* __restrict__ ca,
    float* __restrict__ cb,
    const int* __restrict__ graph, unsigned int* __restrict__ gbase,
    unsigned int* __restrict__ ebuf)
{
    const int t  = threadIdx.x;
    const int bx = blockIdx.x;
    int bi, role;
    if (bx < 1536) {
        int rem = bx & 31;
        role = rem >> 3;
        bi   = (bx >> 5) * 8 + (rem & 7);
    } else {
        int idx = bx - 1536;
        role = idx / 7;
        bi   = 384 + idx - role * 7;
    }

    __shared__ __align__(16) unsigned short Ah[128][40];   // 10 KB
    __shared__ __align__(16) unsigned short Bh[128][40];   // 10 KB

    if (role == 3) {                       // aux path (block-uniform branches)
        unsigned int* hist  = (unsigned int*)&Ah[0][0];    // [512] used: 0..390
        unsigned int* sbase = hist + 512;                  // [512] used: 0..390
        for (int u = t; u < NBK; u += 256) hist[u] = 0u;
        __syncthreads();

        int dsts[8], srcs[8];
        bool ok[8];
        const int e0 = bi * 2048;
#pragma unroll
        for (int u = 0; u < 8; ++u) {
            int e = e0 + u * 256 + t;
            ok[u] = (e < NE);
            if (ok[u]) { dsts[u] = graph[e]; srcs[u] = graph[NE + e]; }
        }
#pragma unroll
        for (int u = 0; u < 8; ++u)
            if (ok[u]) atomicAdd(&hist[dsts[u] >> 7], 1u); // LDS atomic
        __syncthreads();
        for (int u = t; u < NBK; u += 256) {
            unsigned int c = hist[u];
            unsigned int s = c ? atomicAdd(&gbase[u * GB_STRIDE], c) : 0u;  // padded global
            sbase[u] = s;
            hist[u]  = 0u;                                 // reuse as local rank
        }
        __syncthreads();
#pragma unroll
        for (int u = 0; u < 8; ++u)
            if (ok[u]) {
                int b = dsts[u] >> 7;
                unsigned int pos = sbase[b] + atomicAdd(&hist[b], 1u);
                if (pos < CAPB)
                    ebuf[(size_t)b * CAPB + pos] =
                        ((unsigned int)(dsts[u] & 127) << 16) | (unsigned int)srcs[u];
            }

        if (bi < CAB) {
            __shared__ float s_rw[12];
            __shared__ float s_rb[4];
            if (t < 12) {
                int h = t / 3, p = t % 3;
                float s = 0.f;
                for (int d = 0; d < 32; ++d) s += rpe_w[(h * 32 + d) * 3 + p];
                s_rw[t] = s;
            } else if (t < 16) {
                int h = t - 12;
                float s = 0.f;
                for (int d = 0; d < 32; ++d) s += rpe_b[h * 32 + d];
                s_rb[h] = s;
            }
            __syncthreads();
            int n = bi * 256 + t;
            if (n < NN) {
                float c0 = coord[n * 3 + 0], c1 = coord[n * 3 + 1], c2 = coord[n * 3 + 2];
#pragma unroll
                for (int h = 0; h < 4; ++h) {
                    float a = c0 * s_rw[h * 3 + 0] + c1 * s_rw[h * 3 + 1] + c2 * s_rw[h * 3 + 2];
                    ca[n * 4 + h] = a;
                    cb[n * 4 + h] = a + s_rb[h];
                }
            }
        }
        return;
    }

    const int bm = bi * 128;
    const int bc = role * 128;             // 0=q 1=k 2=v

    const int wave = t >> 6;
    const int lane = t & 63;
    const int wr = wave & 1;
    const int wc = wave >> 1;
    const int qd = lane >> 4;
    const int l15 = lane & 15;

    f32x4 acc[4][4];
#pragma unroll
    for (int i = 0; i < 4; ++i)
#pragma unroll
        for (int j = 0; j < 4; ++j)
            acc[i][j] = (f32x4){0.f, 0.f, 0.f, 0.f};

    for (int ks = 0; ks < 4; ++ks) {
        const int k0 = ks * 32;
        if (ks) __syncthreads();
        // stage 128x32 slabs: load fp32, cvt to fp16 inline, write b128 to LDS
#pragma unroll
        for (int c = 0; c < 2; ++c) {
            int idx = c * 256 + t;          // 0..511
            int r  = idx >> 2;
            int c8 = (idx & 3) * 8;
            int ga = bm + r;
            ushort8 a8 = (ushort8){0,0,0,0,0,0,0,0};
            if (ga < NN) {
                const float* ap = feat + (size_t)ga * 128 + k0 + c8;
                float4 x = *(const float4*)ap;
                float4 y = *(const float4*)(ap + 4);
                a8 = (ushort8){f2h(x.x), f2h(x.y), f2h(x.z), f2h(x.w),
                               f2h(y.x), f2h(y.y), f2h(y.z), f2h(y.w)};
            }
            *(ushort8*)&Ah[r][c8] = a8;
            const float* bp = w + (size_t)(bc + r) * 128 + k0 + c8;
            float4 bx2 = *(const float4*)bp;
            float4 by2 = *(const float4*)(bp + 4);
            *(ushort8*)&Bh[r][c8] = (ushort8){f2h(bx2.x), f2h(bx2.y), f2h(bx2.z), f2h(bx2.w),
                                              f2h(by2.x), f2h(by2.y), f2h(by2.z), f2h(by2.w)};
        }
        __syncthreads();
        fp16x8 af[4];
#pragma unroll
        for (int i = 0; i < 4; ++i)
            af[i] = *(const fp16x8*)&Ah[wr * 64 + 16 * i + l15][qd * 8];
#pragma unroll
        for (int j = 0; j < 4; ++j) {
            fp16x8 bf = *(const fp16x8*)&Bh[wc * 64 + 16 * j + l15][qd * 8];
#pragma unroll
            for (int i = 0; i < 4; ++i)
                acc[i][j] = __builtin_amdgcn_mfma_f32_16x16x32_f16(af[i], bf, acc[i][j], 0, 0, 0);
        }
    }

    float bj[4];
#pragma unroll
    for (int j = 0; j < 4; ++j)
        bj[j] = bias[bc + wc * 64 + 16 * j + l15];

    // ---- epilogue: per i-group (32 rows x 128 cols) LDS transpose ----
    unsigned short* Ct = &Ah[0][0];        // Ct[32][136] fp16, overlays Ah
    const int isQ = (role == 0);
    const int half = (role == 1) ? 0 : 128;
    const int relRowW = wr * 16 + qd * 4;

    for (int i = 0; i < 4; ++i) {
        __syncthreads();                   // prior phase's LDS reads done
#pragma unroll
        for (int j = 0; j < 4; ++j) {
            int col = wc * 64 + 16 * j + l15;
#pragma unroll
            for (int rg = 0; rg < 4; ++rg)
                Ct[(relRowW + rg) * 136 + col] = f2h(acc[i][j][rg] + bj[j]);
        }
        __syncthreads();
#pragma unroll
        for (int p = 0; p < 2; ++p) {
            int linear = p * 256 + t;
            int rr = linear >> 4;          // 0..31
            int cc = linear & 15;          // 16B chunk (8 cols)
            int absRow = bm + 16 * i + rr + ((rr >> 4) * 48);
            if (absRow < NN) {
                ushort8 val = *(const ushort8*)&Ct[rr * 136 + cc * 8];
                if (isQ) *(ushort8*)(qbuf16 + (size_t)absRow * 128 + cc * 8) = val;
                else     *(ushort8*)(kvbuf + (size_t)absRow * 256 + half + cc * 8) = val;
            }
        }
    }
}

// ---------------------------------------------------------------------------
// Kernel 2: in-LDS CSR + per-node attention. EXACT r6 structure (quad units,
// 1564 static blocks — the measured optimum of the scan-replication vs
// parallelism trade; r9 octants and r10 halves both regressed).
// SINGLE change vs r6: the ebuf scan reads uint4 (4 edges/load) instead of
// uint — same bytes and filter, 4x fewer VMEM instructions/iterations
// (3.2M -> 800k loads), so the streaming scan retires faster under the
// co-resident gather waves (r9 delta priced scan reads at ~10us per M).
// (r11 run of this exact code died to container infra, not the kernel —
// bounds audit: max scan read = bucket end, ebuf 16B-aligned.)
// ---------------------------------------------------------------------------
__global__ __launch_bounds__(256) void attn_fused(
    const unsigned short* __restrict__ qbuf16, const unsigned short* __restrict__ kvbuf,
    const float* __restrict__ ca, const float* __restrict__ cb,
    const unsigned int* __restrict__ gbase, const unsigned int* __restrict__ ebuf,
    float* __restrict__ out)
{
    __shared__ __align__(16) unsigned short slots[32][64];   // 4 KB
    __shared__ unsigned int ncnt[32];

    const int t    = threadIdx.x;
    const int b    = blockIdx.x >> 2;      // bucket 0..390
    const int quad = blockIdx.x & 3;       // 32-node quadrant

    if (t < 32) ncnt[t] = 0u;
    __syncthreads();

    int total = (int)gbase[b * GB_STRIDE];
    if (total > CAPB) total = CAPB;
    // vectorized scan: 4 edges per load (ebuf rows are 16B-aligned: CAPB*4
    // bytes per bucket, CAPB % 4 == 0)
    const uint4* eb4 = (const uint4*)(ebuf + (size_t)b * CAPB);
    const int nv = (total + 3) >> 2;
    for (int i = t; i < nv; i += 256) {
        uint4 e4 = eb4[i];
        const int base = i * 4;
        unsigned ev[4] = {e4.x, e4.y, e4.z, e4.w};
#pragma unroll
        for (int v = 0; v < 4; ++v) {
            if (base + v < total) {
                unsigned int e = ev[v];
                int dl = (int)(e >> 16);                       // 0..127
                if ((dl >> 5) == quad) {
                    int ldl = dl & 31;
                    unsigned int slot = atomicAdd(&ncnt[ldl], 1u); // LDS atomic
                    if (slot < PAD) slots[ldl][slot] = (unsigned short)(e & 0xFFFFu);
                }
            }
        }
    }
    __syncthreads();

    const int j  = t & 31;
    const int h  = j >> 3;
    const int j8 = j * 8;
    const int h4 = h * 4;
    const int ln = t >> 5;                 // node-within-group 0..7
    const char* kvp = (const char*)kvbuf;
    const char* cap = (const char*)ca;

    for (int g = 0; g < 4; ++g) {
        const int ldl = g * 8 + ln;
        const int n = b * 128 + quad * 32 + ldl;
        if (n >= NN) continue;
        int d = (int)ncnt[ldl];
        if (d > PAD) d = PAD;
        const unsigned short* sl = &slots[ldl][0];

        const uint2 qv = *(const uint2*)((const char*)qbuf16 + (size_t)n * 256 + j8);
        const half2 qh01 = h2(qv.x);
        const half2 qh23 = h2(qv.y);
        const float cbh = cb[n * 4 + h];

        float4 acc = make_float4(0.f, 0.f, 0.f, 0.f);
        float den = 0.f;

        int i = 0;
        for (; i + 7 < d; i += 8) {
            ushort8 s8 = *(const ushort8*)(sl + i);        // LDS, 16B
            unsigned o[8];
#pragma unroll
            for (int v = 0; v < 8; ++v) o[v] = (unsigned)s8[v] << 9;
            uint2 kk[8], vv[8];
            float aa[8];
#pragma unroll
            for (int v = 0; v < 8; ++v) kk[v] = *(const uint2*)(kvp + o[v] + j8);
#pragma unroll
            for (int v = 0; v < 8; ++v) vv[v] = *(const uint2*)(kvp + o[v] + 256 + j8);
#pragma unroll
            for (int v = 0; v < 8; ++v) aa[v] = *(const float*)(cap + (o[v] >> 5) + h4);
            float p[8];
#pragma unroll
            for (int v = 0; v < 8; ++v)
                p[v] = dot2(qh01, h2(kk[v].x), dot2(qh23, h2(kk[v].y), 0.f));
#pragma unroll
            for (int v = 0; v < 8; ++v) p[v] += __shfl_xor(p[v], 1);
#pragma unroll
            for (int v = 0; v < 8; ++v) p[v] += __shfl_xor(p[v], 2);
#pragma unroll
            for (int v = 0; v < 8; ++v) p[v] += __shfl_xor(p[v], 4);
            float e[8];
#pragma unroll
            for (int v = 0; v < 8; ++v) { e[v] = __expf(p[v] + cbh - aa[v]); den += e[v]; }
#pragma unroll
            for (int v = 0; v < 8; ++v) {
                half2 va = h2(vv[v].x);
                half2 vb = h2(vv[v].y);
                acc.x += e[v] * (float)va.x;
                acc.y += e[v] * (float)va.y;
                acc.z += e[v] * (float)vb.x;
                acc.w += e[v] * (float)vb.y;
            }
        }
        for (; i + 3 < d; i += 4) {
            ushort4 s4 = *(const ushort4*)(sl + i);
            unsigned o0 = (unsigned)s4.x << 9;
            unsigned o1 = (unsigned)s4.y << 9;
            unsigned o2 = (unsigned)s4.z << 9;
            unsigned o3 = (unsigned)s4.w << 9;
            uint2 k0 = *(const uint2*)(kvp + o0 + j8);
            uint2 k1 = *(const uint2*)(kvp + o1 + j8);
            uint2 k2 = *(const uint2*)(kvp + o2 + j8);
            uint2 k3 = *(const uint2*)(kvp + o3 + j8);
            uint2 v0 = *(const uint2*)(kvp + o0 + 256 + j8);
            uint2 v1 = *(const uint2*)(kvp + o1 + 256 + j8);
            uint2 v2 = *(const uint2*)(kvp + o2 + 256 + j8);
            uint2 v3 = *(const uint2*)(kvp + o3 + 256 + j8);
            float a0 = *(const float*)(cap + (o0 >> 5) + h4);
            float a1 = *(const float*)(cap + (o1 >> 5) + h4);
            float a2 = *(const float*)(cap + (o2 >> 5) + h4);
            float a3 = *(const float*)(cap + (o3 >> 5) + h4);

            float p0 = dot2(qh01, h2(k0.x), dot2(qh23, h2(k0.y), 0.f));
            float p1 = dot2(qh01, h2(k1.x), dot2(qh23, h2(k1.y), 0.f));
            float p2 = dot2(qh01, h2(k2.x), dot2(qh23, h2(k2.y), 0.f));
            float p3 = dot2(qh01, h2(k3.x), dot2(qh23, h2(k3.y), 0.f));
            p0 += __shfl_xor(p0, 1); p1 += __shfl_xor(p1, 1);
            p2 += __shfl_xor(p2, 1); p3 += __shfl_xor(p3, 1);
            p0 += __shfl_xor(p0, 2); p1 += __shfl_xor(p1, 2);
            p2 += __shfl_xor(p2, 2); p3 += __shfl_xor(p3, 2);
            p0 += __shfl_xor(p0, 4); p1 += __shfl_xor(p1, 4);
            p2 += __shfl_xor(p2, 4); p3 += __shfl_xor(p3, 4);

            float e0 = __expf(p0 + cbh - a0);
            float e1 = __expf(p1 + cbh - a1);
            float e2 = __expf(p2 + cbh - a2);
            float e3 = __expf(p3 + cbh - a3);
            den += (e0 + e1) + (e2 + e3);
            half2 v0a = h2(v0.x), v0b = h2(v0.y);
            half2 v1a = h2(v1.x), v1b = h2(v1.y);
            half2 v2a = h2(v2.x), v2b = h2(v2.y);
            half2 v3a = h2(v3.x), v3b = h2(v3.y);
            acc.x += e0 * (float)v0a.x + e1 * (float)v1a.x + e2 * (float)v2a.x + e3 * (float)v3a.x;
            acc.y += e0 * (float)v0a.y + e1 * (float)v1a.y + e2 * (float)v2a.y + e3 * (float)v3a.y;
            acc.z += e0 * (float)v0b.x + e1 * (float)v1b.x + e2 * (float)v2b.x + e3 * (float)v3b.x;
            acc.w += e0 * (float)v0b.y + e1 * (float)v1b.y + e2 * (float)v2b.y + e3 * (float)v3b.y;
        }
        for (; i < d; ++i) {
            unsigned o0 = (unsigned)sl[i] << 9;
            uint2 k0 = *(const uint2*)(kvp + o0 + j8);
            uint2 v0 = *(const uint2*)(kvp + o0 + 256 + j8);
            float a0 = *(const float*)(cap + (o0 >> 5) + h4);
            float p0 = dot2(qh01, h2(k0.x), dot2(qh23, h2(k0.y), 0.f));
            p0 += __shfl_xor(p0, 1);
            p0 += __shfl_xor(p0, 2);
            p0 += __shfl_xor(p0, 4);
            float e = __expf(p0 + cbh - a0);
            den += e;
            half2 va = h2(v0.x);
            half2 vb = h2(v0.y);
            acc.x += e * (float)va.x;
            acc.y += e * (float)va.y;
            acc.z += e * (float)vb.x;
            acc.w += e * (float)vb.y;
        }

        float inv = (den > 0.f) ? 1.0f / den : 0.f;
        float4 o = make_float4(acc.x * inv, acc.y * inv, acc.z * inv, acc.w * inv);
        ((float4*)(out + (size_t)n * 128))[j] = o;
    }
}

extern "C" void kernel_launch(void* const* d_in, const int* in_sizes, int n_in,
                              void* d_out, int out_size, void* d_ws, size_t ws_size,
                              hipStream_t stream) {
    const float* feat  = (const float*)d_in[0];
    const float* coord = (const float*)d_in[1];
    const int*   graph = (const int*)d_in[2];
    const float* qkv_w = (const float*)d_in[3];
    const float* qkv_b = (const float*)d_in[4];
    const float* rpe_w = (const float*)d_in[5];
    const float* rpe_b = (const float*)d_in[6];
    float* out = (float*)d_out;

    unsigned short* qbuf16 = (unsigned short*)d_ws;                       // NN x 128 f16   (12.8 MB)
    unsigned short* kvbuf  = qbuf16 + (size_t)NN * 128;                   // NN x 256 f16   (25.6 MB)
    float* ca = (float*)(kvbuf + (size_t)NN * 256);                       // NN x 4         (0.8 MB)
    float* cb = ca + (size_t)NN * 4;                                      // NN x 4         (0.8 MB)
    unsigned int* gbase = (unsigned int*)(cb + (size_t)NN * 4);           // NBK x 32       (50 KB)
    unsigned int* ebuf  = gbase + (size_t)NBK * GB_STRIDE;                // NBK x CAPB     (4.0 MB)

    hipMemsetAsync(gbase, 0, (size_t)NBK * GB_STRIDE * sizeof(unsigned int), stream);

    qkv_gemm  <<<dim3(NU), 256, 0, stream>>>(feat, qkv_w, qkv_b, qbuf16, kvbuf,
                                             coord, rpe_w, rpe_b, ca, cb,
                                             graph, gbase, ebuf);
    attn_fused<<<dim3(NBK * 4), 256, 0, stream>>>(qbuf16, kvbuf, ca, cb,
                                                  gbase, ebuf, out);
}